// Round 3
// baseline (4376.568 us; speedup 1.0000x reference)
//
#include <hip/hip_runtime.h>
#include <hip/hip_bf16.h>
#include <math.h>

#define B_    4096
#define Z_    128
#define V_    9
#define HN_   13
#define ED_   5
#define ND_   10
#define HID_  32
#define H_    4
#define D_    32
#define N_    (B_*V_)          // 36864 nodes
#define E_    (B_*V_*V_)       // 331776 edges (with self loops)
#define EK_   (B_*V_*(V_-1))   // 294912 kept edges

// ---------------------------------------------------------------------------
// Batched GEMM for the MLP head: out[M,Nc] = act(A[M,K] @ W[K,Nc] + bias)
// 8 rows per block, act: 0 = none, 1 = tanh.  M = 4096.
// ---------------------------------------------------------------------------
__global__ __launch_bounds__(256) void gemm_act_kernel(
    const float* __restrict__ A, const float* __restrict__ W,
    const float* __restrict__ bias, float* __restrict__ out,
    int K, int Nc, int act)
{
    __shared__ float As[8 * 512];   // max K = 512
    const int row0 = blockIdx.x * 8;
    const int tid  = threadIdx.x;

    for (int idx = tid; idx < 8 * K; idx += 256)
        As[idx] = A[row0 * K + idx];
    __syncthreads();

    const int total = 8 * Nc;
    for (int idx = tid; idx < total; idx += 256) {
        int r = idx / Nc;
        int n = idx - r * Nc;
        float acc = bias[n];
        const float* a = &As[r * K];
        for (int k = 0; k < K; ++k)
            acc = fmaf(a[k], W[k * Nc + n], acc);
        if (act == 1) acc = tanhf(acc);
        out[(row0 + r) * Nc + n] = acc;
    }
}

// ---------------------------------------------------------------------------
// Fully fused GNN: 3 conv layers + final projections + static index outputs.
// One block (256 threads) per graph.  LDS = 17550 floats = 70.2 KB.
// ---------------------------------------------------------------------------
__global__ __launch_bounds__(256) void fused_gnn_kernel(
    const float* __restrict__ nl,    // [B, 117]  node logits
    const float* __restrict__ el,    // [B, 405]  edge logits (pre-symmetrize)
    const float* __restrict__ c0_wq, const float* __restrict__ c0_wk,
    const float* __restrict__ c0_wv, const float* __restrict__ c0_we,
    const float* __restrict__ c0_weo,
    const float* __restrict__ c1_wq, const float* __restrict__ c1_wk,
    const float* __restrict__ c1_wv, const float* __restrict__ c1_we,
    const float* __restrict__ c1_weo,
    const float* __restrict__ ln0_g, const float* __restrict__ ln0_b,
    const float* __restrict__ ln1_g, const float* __restrict__ ln1_b,
    const float* __restrict__ w_feat, const float* __restrict__ w_eout,
    float* __restrict__ out)
{
    __shared__ float sm[17550];
    float* x0s = sm;          // 117   layer-0 x input [9,13]
    float* e0s = sm + 117;    // 405   layer-0 e input [81,5]
    float* xc  = sm + 522;    // 288   current x [9,32]
    float* ec  = sm + 810;    // 2592  current e [81,32]
    float* qb  = sm + 3402;   // 1152  q [9,128]   (aliased as xn [9,32] in P3+)
    float* kb  = sm + 4554;   // 1152  k [9,128]
    float* vb  = sm + 5706;   // 1152  v [9,128]
    float* ehb = sm + 6858;   // 10368 eh [81,128] (aliased as en [81,32] in P4+)
    float* la  = sm + 17226;  // 324   logits -> alpha in place [81,4]

    const int b   = blockIdx.x;
    const int tid = threadIdx.x;

    // stage layer-0 inputs (symmetrize edge logits on the fly)
    for (int idx = tid; idx < 117; idx += 256) x0s[idx] = nl[b * 117 + idx];
    for (int idx = tid; idx < 405; idx += 256) {
        int le = idx / 5, c = idx - le * 5;
        int i = le / 9, j = le - i * 9;
        e0s[idx] = 0.5f * (el[b * 405 + c * 81 + i * 9 + j] +
                           el[b * 405 + c * 81 + j * 9 + i]);
    }
    __syncthreads();

    for (int layer = 0; layer < 3; ++layer) {
        const float *xs, *es, *wq, *wk, *wv, *we, *weo;
        int XD, ED2;
        if (layer == 0) { xs = x0s; es = e0s; XD = 13; ED2 = 5;
                          wq = c0_wq; wk = c0_wk; wv = c0_wv; we = c0_we; weo = c0_weo; }
        else            { xs = xc;  es = ec;  XD = 32; ED2 = 32;
                          wq = c1_wq; wk = c1_wk; wv = c1_wv; we = c1_we; weo = c1_weo; }

        // P1: q,k,v projections (3*9*128) and e projection (81*128)
        for (int idx = tid; idx < 13824; idx += 256) {
            if (idx < 3456) {
                int which = idx / 1152, rem = idx - which * 1152;
                int node = rem >> 7, hd = rem & 127;
                const float* w = (which == 0) ? wq : (which == 1) ? wk : wv;
                float acc = 0.f;
                for (int m = 0; m < XD; ++m)
                    acc = fmaf(xs[node * XD + m], w[m * 128 + hd], acc);
                float* dst = (which == 0) ? qb : (which == 1) ? kb : vb;
                dst[rem] = acc;
            } else {
                int r = idx - 3456;
                int le = r >> 7, hd = r & 127;
                float acc = 0.f;
                for (int m = 0; m < ED2; ++m)
                    acc = fmaf(es[le * ED2 + m], we[m * 128 + hd], acc);
                ehb[r] = acc;
            }
        }
        __syncthreads();

        // P2a: logits[le,h] = (q[dst=j] . (k[src=i]+e)) / sqrt(32)
        for (int idx = tid; idx < 324; idx += 256) {
            int le = idx >> 2, h = idx & 3;
            int i = le / 9, j = le - i * 9;
            const float* qp = &qb[j * 128 + h * 32];
            const float* kp = &kb[i * 128 + h * 32];
            const float* ep = &ehb[le * 128 + h * 32];
            float acc = 0.f;
            for (int d = 0; d < 32; ++d) acc = fmaf(qp[d], kp[d] + ep[d], acc);
            la[idx] = acc * 0.17677669529663687f;
        }
        __syncthreads();

        // P2b: segment softmax over src i, per (dst j, head h), in place
        for (int s = tid; s < 36; s += 256) {
            int j = s >> 2, h = s & 3;
            float m = -1e30f;
            for (int i = 0; i < 9; ++i) m = fmaxf(m, la[(i * 9 + j) * 4 + h]);
            float ex[9], sum = 0.f;
            for (int i = 0; i < 9; ++i) { ex[i] = expf(la[(i * 9 + j) * 4 + h] - m); sum += ex[i]; }
            float inv = 1.f / (sum + 1e-16f);
            for (int i = 0; i < 9; ++i) la[(i * 9 + j) * 4 + h] = ex[i] * inv;
        }
        __syncthreads();

        // P3: aggregation -> xn (aliases qb; qb dead, reads la/vb/ehb only)
        for (int idx = tid; idx < 288; idx += 256) {
            int j = idx >> 5, d = idx & 31;
            float acc = 0.f;
            for (int h = 0; h < 4; ++h)
                for (int i = 0; i < 9; ++i) {
                    int le = i * 9 + j;
                    acc = fmaf(la[le * 4 + h],
                               vb[i * 128 + h * 32 + d] + ehb[le * 128 + h * 32 + d], acc);
                }
            qb[idx] = acc * 0.25f;   // xn
        }
        __syncthreads();   // ehb reads done before P4 overwrites it

        // P4: edge out = concat(x[src], x[dst], e) @ weo -> en (aliases ehb)
        for (int idx = tid; idx < 2592; idx += 256) {
            int le = idx >> 5, c = idx & 31;
            int i = le / 9, j = le - i * 9;
            float acc = 0.f;
            for (int m = 0; m < XD;  ++m) acc = fmaf(xs[i * XD + m],   weo[m * 32 + c], acc);
            for (int m = 0; m < XD;  ++m) acc = fmaf(xs[j * XD + m],   weo[(XD + m) * 32 + c], acc);
            for (int m = 0; m < ED2; ++m) acc = fmaf(es[le * ED2 + m], weo[(2 * XD + m) * 32 + c], acc);
            ehb[idx] = acc;   // en
        }
        __syncthreads();   // xs/es reads done before P5 overwrites xc/ec

        // P5 (layers 0,1 only): x = leaky(LN(xn)), e = leaky(en)
        if (layer < 2) {
            const float* g  = (layer == 0) ? ln0_g : ln1_g;
            const float* be = (layer == 0) ? ln0_b : ln1_b;
            for (int idx = tid; idx < 288; idx += 256) {
                int j = idx >> 5, c = idx & 31;
                float mu = 0.f;
                for (int t = 0; t < 32; ++t) mu += qb[j * 32 + t];
                mu *= (1.f / 32.f);
                float var = 0.f;
                for (int t = 0; t < 32; ++t) { float d = qb[j * 32 + t] - mu; var = fmaf(d, d, var); }
                var *= (1.f / 32.f);
                float val = (qb[idx] - mu) / sqrtf(var + 1e-5f);
                val = val * g[c] + be[c];
                xc[idx] = (val > 0.f) ? val : 0.01f * val;
            }
            for (int idx = tid; idx < 2592; idx += 256) {
                float v = ehb[idx];
                ec[idx] = (v > 0.f) ? v : 0.01f * v;
            }
            __syncthreads();
        }
    }

    // Finals.  After layer 2 (no post): xn = qb[9*32] raw, en = ehb[81*32] raw.
    // d_out is FLOAT32 (evidence: out_npz 6.99 MB > bf16 raw 4.94 MB).
    float* out_x  = out;                       // [36864,10]
    float* out_e  = out + 368640;              // [294912,5]
    float* out_ei = out + 1843200;             // [2,294912]
    float* out_b  = out + 2433024;             // [36864]

    for (int idx = tid; idx < 90; idx += 256) {         // x @ w_feat
        int j = idx / 10, c = idx - j * 10;
        float acc = 0.f;
        for (int kk = 0; kk < 32; ++kk) acc = fmaf(qb[j * 32 + kk], w_feat[kk * 10 + c], acc);
        out_x[(b * 9 + j) * 10 + c] = acc;
    }
    for (int idx = tid; idx < 360; idx += 256) {        // masked eattr @ w_eout
        int r = idx / 5, c = idx - r * 5;
        int i = r >> 3, jj = r & 7;
        int j = jj + (jj >= i ? 1 : 0);
        const float* row = &ehb[(i * 9 + j) * 32];
        float acc = 0.f;
        for (int kk = 0; kk < 32; ++kk) acc = fmaf(row[kk], w_eout[kk * 5 + c], acc);
        out_e[(b * 72 + r) * 5 + c] = acc;
    }
    for (int idx = tid; idx < 72; idx += 256) {         // edge_index (src row, dst row)
        int i = idx >> 3, jj = idx & 7;
        int j = jj + (jj >= i ? 1 : 0);
        out_ei[b * 72 + idx]          = (float)(b * 9 + i);
        out_ei[294912 + b * 72 + idx] = (float)(b * 9 + j);
    }
    for (int idx = tid; idx < 9; idx += 256)            // batch
        out_b[b * 9 + idx] = (float)b;
}

// ---------------------------------------------------------------------------
extern "C" void kernel_launch(void* const* d_in, const int* in_sizes, int n_in,
                              void* d_out, int out_size, void* d_ws, size_t ws_size,
                              hipStream_t stream)
{
    const float* latent  = (const float*)d_in[0];
    const float* w_mlp0  = (const float*)d_in[1];
    const float* b_mlp0  = (const float*)d_in[2];
    const float* w_mlp1  = (const float*)d_in[3];
    const float* b_mlp1  = (const float*)d_in[4];
    const float* w_mlp2  = (const float*)d_in[5];
    const float* b_mlp2  = (const float*)d_in[6];
    const float* w_edges = (const float*)d_in[7];
    const float* b_edges = (const float*)d_in[8];
    const float* w_nodes = (const float*)d_in[9];
    const float* b_nodes = (const float*)d_in[10];
    const float* c0_wq   = (const float*)d_in[11];
    const float* c0_wk   = (const float*)d_in[12];
    const float* c0_wv   = (const float*)d_in[13];
    const float* c0_we   = (const float*)d_in[14];
    const float* c0_weo  = (const float*)d_in[15];
    const float* c1_wq   = (const float*)d_in[16];
    const float* c1_wk   = (const float*)d_in[17];
    const float* c1_wv   = (const float*)d_in[18];
    const float* c1_we   = (const float*)d_in[19];
    const float* c1_weo  = (const float*)d_in[20];
    const float* ln0_g   = (const float*)d_in[21];
    const float* ln0_b   = (const float*)d_in[22];
    const float* ln1_g   = (const float*)d_in[23];
    const float* ln1_b   = (const float*)d_in[24];
    const float* w_feat  = (const float*)d_in[25];
    const float* w_eout  = (const float*)d_in[26];

    // Workspace layout with lifetime overlap (peak 4,804,608 floats = 18.3 MB):
    //   h0 [0,      524288)   live steps 1-2
    //   el [0,     1658880)   live steps 4-end   (h0 dead)
    //   h1 [1658880,2707456)  live steps 2-3
    //   nl [1658880,2138112)  live steps 5-end   (h1 dead)
    //   h2 [2707456,4804608)  live steps 3-5
    float* ws = (float*)d_ws;
    float* h0 = ws;
    float* el = ws;
    float* h1 = ws + 1658880;
    float* nl = ws + 1658880;
    float* h2 = ws + 2707456;

    float* out = (float*)d_out;

    // Stage 1: tanh MLP (step 1..3), then node/edge logits (4..5)
    gemm_act_kernel<<<512, 256, 0, stream>>>(latent, w_mlp0, b_mlp0, h0, 128, 128, 1);
    gemm_act_kernel<<<512, 256, 0, stream>>>(h0, w_mlp1, b_mlp1, h1, 128, 256, 1);
    gemm_act_kernel<<<512, 256, 0, stream>>>(h1, w_mlp2, b_mlp2, h2, 256, 512, 1);
    gemm_act_kernel<<<512, 256, 0, stream>>>(h2, w_edges, b_edges, el, 512, 405, 0);
    gemm_act_kernel<<<512, 256, 0, stream>>>(h2, w_nodes, b_nodes, nl, 512, 117, 0);

    // Stage 2: fused 3-layer GNN + all outputs, one block per graph
    fused_gnn_kernel<<<B_, 256, 0, stream>>>(nl, el,
        c0_wq, c0_wk, c0_wv, c0_we, c0_weo,
        c1_wq, c1_wk, c1_wv, c1_we, c1_weo,
        ln0_g, ln0_b, ln1_g, ln1_b, w_feat, w_eout, out);
}

// Round 7
// 4130.601 us; speedup vs baseline: 1.0595x; 1.0595x over previous
//
#include <hip/hip_runtime.h>
#include <hip/hip_bf16.h>
#include <math.h>

#define B_    4096
#define Z_    128
#define V_    9
#define HN_   13
#define ED_   5
#define ND_   10
#define HID_  32
#define H_    4
#define D_    32
#define N_    (B_*V_)          // 36864 nodes
#define E_    (B_*V_*V_)       // 331776 edges (with self loops)
#define EK_   (B_*V_*(V_-1))   // 294912 kept edges

// ---------------------------------------------------------------------------
// Batched GEMM for the MLP head: out[M,Nc] = act(A[M,K] @ W[K,Nc] + bias)
// 8 rows per block, act: 0 = none, 1 = tanh.  M = 4096.
// ---------------------------------------------------------------------------
__global__ __launch_bounds__(256) void gemm_act_kernel(
    const float* __restrict__ A, const float* __restrict__ W,
    const float* __restrict__ bias, float* __restrict__ out,
    int K, int Nc, int act)
{
    __shared__ float As[8 * 512];   // max K = 512
    const int row0 = blockIdx.x * 8;
    const int tid  = threadIdx.x;

    for (int idx = tid; idx < 8 * K; idx += 256)
        As[idx] = A[row0 * K + idx];
    __syncthreads();

    const int total = 8 * Nc;
    for (int idx = tid; idx < total; idx += 256) {
        int r = idx / Nc;
        int n = idx - r * Nc;
        float acc = bias[n];
        const float* a = &As[r * K];
        for (int k = 0; k < K; ++k)
            acc = fmaf(a[k], W[k * Nc + n], acc);
        if (act == 1) acc = tanhf(acc);
        out[(row0 + r) * Nc + n] = acc;
    }
}

// ---------------------------------------------------------------------------
// Fully fused GNN: 3 conv layers + final projections + static index outputs.
// One block (512 threads) per graph.  LDS = 18094 floats = 72.4 KB.
// q/k/v stored transposed+padded:  qT[d*37 + node*4 + h]   (37 % 32 = 5, coprime)
// e   stored transposed+padded:    eT[d*329 + le*4 + h]    (329 % 32 = 9, coprime)
// -> P1 writes and P2a/P3 reads are bank-conflict-free (lane-varying part
//    spans distinct banks; equal addresses broadcast).
// ---------------------------------------------------------------------------
__global__ __launch_bounds__(512) void fused_gnn_kernel(
    const float* __restrict__ nl,    // [B, 117]  node logits
    const float* __restrict__ el,    // [B, 405]  edge logits (pre-symmetrize)
    const float* __restrict__ c0_wq, const float* __restrict__ c0_wk,
    const float* __restrict__ c0_wv, const float* __restrict__ c0_we,
    const float* __restrict__ c0_weo,
    const float* __restrict__ c1_wq, const float* __restrict__ c1_wk,
    const float* __restrict__ c1_wv, const float* __restrict__ c1_we,
    const float* __restrict__ c1_weo,
    const float* __restrict__ ln0_g, const float* __restrict__ ln0_b,
    const float* __restrict__ ln1_g, const float* __restrict__ ln1_b,
    const float* __restrict__ w_feat, const float* __restrict__ w_eout,
    float* __restrict__ out)
{
    __shared__ float sm[18094];
    float* x0s = sm;           // 117    layer-0 x input [9,13]
    float* e0s = sm + 117;     // 405    layer-0 e input [81,5]
    float* xc  = sm + 522;     // 288    current x [9,32]
    float* ec  = sm + 810;     // 2592   current e [81,32]
    float* qT  = sm + 3402;    // 1184   qT[d*37 + node*4 + h]
    float* kT  = sm + 4586;    // 1184
    float* vT  = sm + 5770;    // 1184
    float* eT  = sm + 6954;    // 10528  eT[d*329 + le*4 + h]; aliased as en[2592] in P4+
    float* xn  = sm + 17482;   // 288    attention out [9,32]
    float* la  = sm + 17770;   // 324    logits -> alpha in place [81,4]
    float* en  = eT;           // edge-out [81,32] (eT dead after P3)

    const int b   = blockIdx.x;
    const int tid = threadIdx.x;

    // stage layer-0 inputs (symmetrize edge logits on the fly)
    for (int idx = tid; idx < 117; idx += 512) x0s[idx] = nl[b * 117 + idx];
    for (int idx = tid; idx < 405; idx += 512) {
        int le = idx / 5, c = idx - le * 5;
        int i = le / 9, j = le - i * 9;
        e0s[idx] = 0.5f * (el[b * 405 + c * 81 + i * 9 + j] +
                           el[b * 405 + c * 81 + j * 9 + i]);
    }
    __syncthreads();

    for (int layer = 0; layer < 3; ++layer) {
        const float *xs, *es, *wq, *wk, *wv, *we, *weo;
        int XD, ED2;
        if (layer == 0) { xs = x0s; es = e0s; XD = 13; ED2 = 5;
                          wq = c0_wq; wk = c0_wk; wv = c0_wv; we = c0_we; weo = c0_weo; }
        else            { xs = xc;  es = ec;  XD = 32; ED2 = 32;
                          wq = c1_wq; wk = c1_wk; wv = c1_wv; we = c1_we; weo = c1_weo; }

        // P1: q,k,v projections (3*9*128) and e projection (81*128),
        // written transposed+padded.
        for (int idx = tid; idx < 13824; idx += 512) {
            if (idx < 3456) {
                int which = idx / 1152, rem = idx - which * 1152;
                int node = rem >> 7, hd = rem & 127;
                int h = hd >> 5, d = hd & 31;
                const float* w = (which == 0) ? wq : (which == 1) ? wk : wv;
                float acc = 0.f;
                for (int m = 0; m < XD; ++m)
                    acc = fmaf(xs[node * XD + m], w[m * 128 + hd], acc);
                float* dst = (which == 0) ? qT : (which == 1) ? kT : vT;
                dst[d * 37 + node * 4 + h] = acc;
            } else {
                int r = idx - 3456;
                int le = r >> 7, hd = r & 127;
                int h = hd >> 5, d = hd & 31;
                float acc = 0.f;
                for (int m = 0; m < ED2; ++m)
                    acc = fmaf(es[le * ED2 + m], we[m * 128 + hd], acc);
                eT[d * 329 + le * 4 + h] = acc;
            }
        }
        __syncthreads();

        // P2a: logits[le,h] = (q[dst=j] . (k[src=i]+e)) / sqrt(32)
        for (int idx = tid; idx < 324; idx += 512) {
            int le = idx >> 2, h = idx & 3;
            int i = le / 9, j = le - i * 9;
            float acc = 0.f;
            for (int d = 0; d < 32; ++d)
                acc = fmaf(qT[d * 37 + j * 4 + h],
                           kT[d * 37 + i * 4 + h] + eT[d * 329 + le * 4 + h], acc);
            la[idx] = acc * 0.17677669529663687f;
        }
        __syncthreads();

        // P2b: segment softmax over src i, per (dst j, head h), in place
        for (int s = tid; s < 36; s += 512) {
            int j = s >> 2, h = s & 3;
            float m = -1e30f;
            for (int i = 0; i < 9; ++i) m = fmaxf(m, la[(i * 9 + j) * 4 + h]);
            float ex[9], sum = 0.f;
            for (int i = 0; i < 9; ++i) { ex[i] = expf(la[(i * 9 + j) * 4 + h] - m); sum += ex[i]; }
            float inv = 1.f / (sum + 1e-16f);
            for (int i = 0; i < 9; ++i) la[(i * 9 + j) * 4 + h] = ex[i] * inv;
        }
        __syncthreads();

        // P3: aggregation -> xn[j,d] = mean_h sum_i alpha * (v[i]+e[le])
        for (int idx = tid; idx < 288; idx += 512) {
            int j = idx >> 5, d = idx & 31;
            float acc = 0.f;
            for (int h = 0; h < 4; ++h)
                for (int i = 0; i < 9; ++i) {
                    int le = i * 9 + j;
                    acc = fmaf(la[le * 4 + h],
                               vT[d * 37 + i * 4 + h] + eT[d * 329 + le * 4 + h], acc);
                }
            xn[idx] = acc * 0.25f;
        }
        __syncthreads();   // eT reads done before P4 overwrites it

        // P4: edge out = concat(x[src], x[dst], e) @ weo -> en (aliases eT)
        for (int idx = tid; idx < 2592; idx += 512) {
            int le = idx >> 5, c = idx & 31;
            int i = le / 9, j = le - i * 9;
            float acc = 0.f;
            for (int m = 0; m < XD;  ++m) acc = fmaf(xs[i * XD + m],   weo[m * 32 + c], acc);
            for (int m = 0; m < XD;  ++m) acc = fmaf(xs[j * XD + m],   weo[(XD + m) * 32 + c], acc);
            for (int m = 0; m < ED2; ++m) acc = fmaf(es[le * ED2 + m], weo[(2 * XD + m) * 32 + c], acc);
            en[idx] = acc;
        }
        __syncthreads();   // xs/es reads done before P5 overwrites xc/ec

        // P5 (layers 0,1 only): x = leaky(LN(xn)), e = leaky(en)
        if (layer < 2) {
            const float* g  = (layer == 0) ? ln0_g : ln1_g;
            const float* be = (layer == 0) ? ln0_b : ln1_b;
            for (int idx = tid; idx < 288; idx += 512) {
                int j = idx >> 5, c = idx & 31;
                float mu = 0.f;
                for (int t = 0; t < 32; ++t) mu += xn[j * 32 + t];
                mu *= (1.f / 32.f);
                float var = 0.f;
                for (int t = 0; t < 32; ++t) { float d = xn[j * 32 + t] - mu; var = fmaf(d, d, var); }
                var *= (1.f / 32.f);
                float val = (xn[idx] - mu) / sqrtf(var + 1e-5f);
                val = val * g[c] + be[c];
                xc[idx] = (val > 0.f) ? val : 0.01f * val;
            }
            for (int idx = tid; idx < 2592; idx += 512) {
                float v = en[idx];
                ec[idx] = (v > 0.f) ? v : 0.01f * v;
            }
            __syncthreads();
        }
    }

    // Finals.  After layer 2 (no post): xn [9,32] raw, en [81,32] raw.
    float* out_x  = out;                       // [36864,10]
    float* out_e  = out + 368640;              // [294912,5]
    float* out_ei = out + 1843200;             // [2,294912]
    float* out_b  = out + 2433024;             // [36864]

    for (int idx = tid; idx < 90; idx += 512) {         // x @ w_feat
        int j = idx / 10, c = idx - j * 10;
        float acc = 0.f;
        for (int kk = 0; kk < 32; ++kk) acc = fmaf(xn[j * 32 + kk], w_feat[kk * 10 + c], acc);
        out_x[(b * 9 + j) * 10 + c] = acc;
    }
    for (int idx = tid; idx < 360; idx += 512) {        // masked eattr @ w_eout
        int r = idx / 5, c = idx - r * 5;
        int i = r >> 3, jj = r & 7;
        int j = jj + (jj >= i ? 1 : 0);
        const float* row = &en[(i * 9 + j) * 32];
        float acc = 0.f;
        for (int kk = 0; kk < 32; ++kk) acc = fmaf(row[kk], w_eout[kk * 5 + c], acc);
        out_e[(b * 72 + r) * 5 + c] = acc;
    }
    for (int idx = tid; idx < 72; idx += 512) {         // edge_index (src row, dst row)
        int i = idx >> 3, jj = idx & 7;
        int j = jj + (jj >= i ? 1 : 0);
        out_ei[b * 72 + idx]          = (float)(b * 9 + i);
        out_ei[294912 + b * 72 + idx] = (float)(b * 9 + j);
    }
    for (int idx = tid; idx < 9; idx += 512)            // batch
        out_b[b * 9 + idx] = (float)b;
}

// ---------------------------------------------------------------------------
extern "C" void kernel_launch(void* const* d_in, const int* in_sizes, int n_in,
                              void* d_out, int out_size, void* d_ws, size_t ws_size,
                              hipStream_t stream)
{
    const float* latent  = (const float*)d_in[0];
    const float* w_mlp0  = (const float*)d_in[1];
    const float* b_mlp0  = (const float*)d_in[2];
    const float* w_mlp1  = (const float*)d_in[3];
    const float* b_mlp1  = (const float*)d_in[4];
    const float* w_mlp2  = (const float*)d_in[5];
    const float* b_mlp2  = (const float*)d_in[6];
    const float* w_edges = (const float*)d_in[7];
    const float* b_edges = (const float*)d_in[8];
    const float* w_nodes = (const float*)d_in[9];
    const float* b_nodes = (const float*)d_in[10];
    const float* c0_wq   = (const float*)d_in[11];
    const float* c0_wk   = (const float*)d_in[12];
    const float* c0_wv   = (const float*)d_in[13];
    const float* c0_we   = (const float*)d_in[14];
    const float* c0_weo  = (const float*)d_in[15];
    const float* c1_wq   = (const float*)d_in[16];
    const float* c1_wk   = (const float*)d_in[17];
    const float* c1_wv   = (const float*)d_in[18];
    const float* c1_we   = (const float*)d_in[19];
    const float* c1_weo  = (const float*)d_in[20];
    const float* ln0_g   = (const float*)d_in[21];
    const float* ln0_b   = (const float*)d_in[22];
    const float* ln1_g   = (const float*)d_in[23];
    const float* ln1_b   = (const float*)d_in[24];
    const float* w_feat  = (const float*)d_in[25];
    const float* w_eout  = (const float*)d_in[26];

    // Workspace layout with lifetime overlap (peak 4,804,608 floats = 18.3 MB):
    //   h0 [0,      524288)   live steps 1-2
    //   el [0,     1658880)   live steps 4-end   (h0 dead)
    //   h1 [1658880,2707456)  live steps 2-3
    //   nl [1658880,2138112)  live steps 5-end   (h1 dead)
    //   h2 [2707456,4804608)  live steps 3-5
    float* ws = (float*)d_ws;
    float* h0 = ws;
    float* el = ws;
    float* h1 = ws + 1658880;
    float* nl = ws + 1658880;
    float* h2 = ws + 2707456;

    float* out = (float*)d_out;

    // Stage 1: tanh MLP (step 1..3), then node/edge logits (4..5)
    gemm_act_kernel<<<512, 256, 0, stream>>>(latent, w_mlp0, b_mlp0, h0, 128, 128, 1);
    gemm_act_kernel<<<512, 256, 0, stream>>>(h0, w_mlp1, b_mlp1, h1, 128, 256, 1);
    gemm_act_kernel<<<512, 256, 0, stream>>>(h1, w_mlp2, b_mlp2, h2, 256, 512, 1);
    gemm_act_kernel<<<512, 256, 0, stream>>>(h2, w_edges, b_edges, el, 512, 405, 0);
    gemm_act_kernel<<<512, 256, 0, stream>>>(h2, w_nodes, b_nodes, nl, 512, 117, 0);

    // Stage 2: fused 3-layer GNN + all outputs, one block per graph
    fused_gnn_kernel<<<B_, 512, 0, stream>>>(nl, el,
        c0_wq, c0_wk, c0_wv, c0_we, c0_weo,
        c1_wq, c1_wk, c1_wv, c1_we, c1_weo,
        ln0_g, ln0_b, ln1_g, ln1_b, w_feat, w_eout, out);
}